// Round 9
// baseline (183.169 us; speedup 1.0000x reference)
//
#include <hip/hip_runtime.h>

// MultiModelMLP, round 8b: memset + 2 kernels, register-resident mlp.
// Key idea: the MFMA D->B inter-layer layout transform is the lane-local
// bijection phi(16mt+4q+r) = 32(mt>>1)+8q+4(mt&1)+r. Storing every layer's
// A-tile rows pre-permuted by phi (and LN consts likewise) makes the lane's
// packed D values exactly the next layer's B-fragment: no LDS, no barriers,
// no shuffles for the transform. LN mean/var are permutation-invariant.

#define NM    64
#define HIDD  64
#define INF   6
#define OUTF  3
#define CAP   4864            // per-model capacity: mean 4096 + 12 sigma
#define NBLKB 128             // bucket kernel grid (2 blocks per model image)

#define CSTRIDE   32
#define O_CURSORS 0           // 64 cursors, stride 32 ints; final = count
#define O_ORDER   2048        // NM*CAP sample ids
#define IWS_INTS  (O_ORDER + NM * CAP)
// then: xs fp16[NM*CAP*8] (packed L0 inputs), then weight image.

// fp16 image per model, fragment-major (slot s in [0,1920), lane l = s&63
// holds its v8h at half-offset s*8); A-tile rows permuted by phi:
//   f = s>>6:  f<4: L0 mt=f (K padded 6->32)
//              f<28: L1..3: l=(f-4)>>3, mt=((f-4)&7)>>1, kh=(f-4)&1
//              else: L4 kh=f-28 (rows physical, padded 3->16)
// floats at byte CONST_B: l=0..3 {bias[64], g[64], h[64]} (phi-permuted),
// B4[3], pad.
#define CONST_B   30720
#define NCONSTF   784
#define IMG_BYTES 33856

typedef _Float16 v8h __attribute__((ext_vector_type(8)));
typedef __fp16   v2hf __attribute__((ext_vector_type(2)));
typedef float    v4f __attribute__((ext_vector_type(4)));

__device__ __host__ __forceinline__ int phi(int p) {
    int mt = p >> 4, q = (p >> 2) & 3, r = p & 3;
    return ((mt >> 1) << 5) | (q << 3) | ((mt & 1) << 2) | r;
}

// ------------------------------------------------------------ kernel 1 ----
__global__ __launch_bounds__(256, 4) void bucket_img_kernel(
    const int* __restrict__ idx, const float* __restrict__ x, int n,
    const float* __restrict__ W0, const float* __restrict__ W1,
    const float* __restrict__ W2, const float* __restrict__ W3,
    const float* __restrict__ W4,
    const float* __restrict__ B0, const float* __restrict__ G0, const float* __restrict__ H0,
    const float* __restrict__ B1, const float* __restrict__ G1, const float* __restrict__ H1,
    const float* __restrict__ B2, const float* __restrict__ G2, const float* __restrict__ H2,
    const float* __restrict__ B3, const float* __restrict__ G3, const float* __restrict__ H3,
    const float* __restrict__ B4,
    int* __restrict__ iws, _Float16* __restrict__ xs,
    unsigned char* __restrict__ imgbase) {
    __shared__ int lcnt[NM], lcur[NM];
    const int b = blockIdx.x, t = threadIdx.x;
    const int m = b >> 1, sub = b & 1;        // 2 blocks build each model image

    // ---- fragment-major image, rows phi-permuted ----
    _Float16* img = (_Float16*)(imgbase + (size_t)m * IMG_BYTES);
    float* cst = (float*)(imgbase + (size_t)m * IMG_BYTES + CONST_B);
    for (int s = sub * 256 + t; s < 1920; s += 512) {
        int f = s >> 6, l = s & 63;
        int c = l & 15, q = l >> 4;
        float vals[8];
        if (f < 4) {                          // layer 0, mt = f
            const float* wr = W0 + m * 384 + phi(f * 16 + c) * 6;
#pragma unroll
            for (int j = 0; j < 8; j++) {
                int k = q * 8 + j;
                vals[j] = (k < INF) ? wr[k] : 0.0f;
            }
        } else if (f < 28) {                  // layers 1..3
            int ll = (f - 4) >> 3, fb = (f - 4) & 7;
            int mt = fb >> 1, kh = fb & 1;
            const float* W = (ll == 0) ? W1 : (ll == 1) ? W2 : W3;
            const float* wr = W + m * 4096 + phi(mt * 16 + c) * 64 + kh * 32 + q * 8;
#pragma unroll
            for (int j = 0; j < 8; j++) vals[j] = wr[j];
        } else {                              // layer 4 (rows physical)
            int kh = f - 28;
            const float* wr = W4 + m * 192 + c * 64 + kh * 32 + q * 8;
#pragma unroll
            for (int j = 0; j < 8; j++) vals[j] = (c < OUTF) ? wr[j] : 0.0f;
        }
        v8h o;
#pragma unroll
        for (int j = 0; j < 8; j++) o[j] = (_Float16)vals[j];
        *(v8h*)(img + (size_t)s * 8) = o;
    }
    for (int e = sub * 256 + t; e < NCONSTF; e += 512) {   // consts, permuted
        const float* lsrc[12] = {B0, G0, H0, B1, G1, H1, B2, G2, H2, B3, G3, H3};
        float v = 0.0f;
        if (e < 768) {
            int l = e / 192, r = e - l * 192;
            v = lsrc[l * 3 + (r >> 6)][m * 64 + phi(r & 63)];
        } else if (e < 771) {
            v = B4[m * 3 + (e - 768)];
        }
        cst[e] = v;
    }

    // ---- pass 1: count this block's segment ----
    if (t < NM) lcnt[t] = 0;
    __syncthreads();
    const int per = (n + NBLKB - 1) / NBLKB;   // 2048
    const int beg = b * per, end = min(n, beg + per);
    for (int i = beg + t; i < end; i += 256) atomicAdd(&lcnt[idx[i]], 1);
    __syncthreads();
    if (t < NM) lcur[t] = atomicAdd(&iws[O_CURSORS + t * CSTRIDE], lcnt[t]);
    __syncthreads();
    // ---- pass 2: scatter ids + packed fp16 x ----
    for (int i = beg + t; i < end; i += 256) {
        int mm = idx[i];
        int r = atomicAdd(&lcur[mm], 1);      // LDS
        int slot = mm * CAP + r;
        iws[O_ORDER + slot] = i;
        const float* xp = x + (size_t)i * 6;
        float2 a0 = *(const float2*)(xp);
        float2 a1 = *(const float2*)(xp + 2);
        float2 a2 = *(const float2*)(xp + 4);
        v8h o = {};
        o[0] = (_Float16)a0.x; o[1] = (_Float16)a0.y;
        o[2] = (_Float16)a1.x; o[3] = (_Float16)a1.y;
        o[4] = (_Float16)a2.x; o[5] = (_Float16)a2.y;
        *(v8h*)(xs + (size_t)slot * 8) = o;
    }
}

// ------------------------------------------------------------ kernel 2 ----
// Epilogue: LN over the 64 (phi-permuted) features + relu + pack straight
// into the next layer's B-fragments. y = fma(fma(D, rs, -mu*rs), g, h).
__device__ __forceinline__ void layer_epilogue(const v4f D[4],
                                               const float* __restrict__ cb,
                                               int q, v8h* __restrict__ pb0,
                                               v8h* __restrict__ pb1) {
    float S = 0.0f, Q2 = 0.0f;
#pragma unroll
    for (int mt = 0; mt < 4; mt++)
#pragma unroll
        for (int r = 0; r < 4; r++) {
            float v = D[mt][r];
            S += v;
            Q2 = fmaf(v, v, Q2);
        }
    S += __shfl_xor(S, 16, 64);
    S += __shfl_xor(S, 32, 64);
    Q2 += __shfl_xor(Q2, 16, 64);
    Q2 += __shfl_xor(Q2, 32, 64);
    float mu = S * (1.0f / 64.0f);
    float var = Q2 * (1.0f / 64.0f) - mu * mu;
    float rs = rsqrtf(var + 1e-5f);
    float nm = -mu * rs;
    union { v8h v; v2hf p[4]; } u0, u1;
#pragma unroll
    for (int mt = 0; mt < 4; mt++) {
        v4f g = *(const v4f*)(cb + 64 + mt * 16 + q * 4);
        v4f h = *(const v4f*)(cb + 128 + mt * 16 + q * 4);
        float y[4];
#pragma unroll
        for (int r = 0; r < 4; r++) {
            float tt = fmaf(D[mt][r], rs, nm);
            y[r] = fmaxf(fmaf(tt, g[r], h[r]), 0.0f);
        }
        v2hf p0 = __builtin_amdgcn_cvt_pkrtz(y[0], y[1]);
        v2hf p1 = __builtin_amdgcn_cvt_pkrtz(y[2], y[3]);
        if (mt < 2) { u0.p[mt * 2] = p0; u0.p[mt * 2 + 1] = p1; }
        else        { u1.p[(mt - 2) * 2] = p0; u1.p[(mt - 2) * 2 + 1] = p1; }
    }
    *pb0 = u0.v;
    *pb1 = u1.v;
}

__global__ __launch_bounds__(256, 4) void mlp_kernel(
    const int* __restrict__ iws, const _Float16* __restrict__ xs,
    const unsigned char* __restrict__ imgbase, float* __restrict__ out) {
    const int m = blockIdx.y;
    const int cnt = iws[O_CURSORS + m * CSTRIDE];
    const int beg = m * CAP, end = beg + cnt;
    const int base = beg + blockIdx.x * 256;
    if (base >= end) return;

    const int t = threadIdx.x, w = t >> 6, lane = t & 63;
    const int c = lane & 15, q = lane >> 4;
    const int wbase = base + w * 64;
    if (wbase >= end) return;

    const _Float16* img = (const _Float16*)(imgbase + (size_t)m * IMG_BYTES);
    const float* cf = (const float*)(imgbase + (size_t)m * IMG_BYTES + CONST_B);
    const int* order = iws + O_ORDER;

    int sid[4], sp[4];
#pragma unroll
    for (int ti = 0; ti < 4; ti++) {
        int p = wbase + ti * 16 + c;
        sp[ti] = p < end ? p : end - 1;
        sid[ti] = order[sp[ti]];
    }

    v8h b0[4], b1[4];

    // ---- layer 0: K=6 padded to 32; B from packed xs ----
    {
        v8h A[4];
#pragma unroll
        for (int mt = 0; mt < 4; mt++)
            A[mt] = *(const v8h*)(img + mt * 512 + lane * 8);
        v4f bias[4];
#pragma unroll
        for (int mt = 0; mt < 4; mt++)
            bias[mt] = *(const v4f*)(cf + mt * 16 + q * 4);
#pragma unroll
        for (int ti = 0; ti < 4; ti++) {
            v8h bfr = {};
            if (q == 0) bfr = *(const v8h*)(xs + (size_t)sp[ti] * 8);
            v4f D[4];
#pragma unroll
            for (int mt = 0; mt < 4; mt++)
                D[mt] = __builtin_amdgcn_mfma_f32_16x16x32_f16(A[mt], bfr, bias[mt], 0, 0, 0);
            layer_epilogue(D, cf, q, &b0[ti], &b1[ti]);
        }
    }

    // ---- layers 1..3: register-resident chaining, no LDS anywhere ----
#pragma unroll
    for (int l = 1; l <= 3; l++) {
        const _Float16* wp = img + 2048 + (l - 1) * 4096 + lane * 8;
        v8h A[4][2];
#pragma unroll
        for (int mt = 0; mt < 4; mt++)
#pragma unroll
            for (int kh = 0; kh < 2; kh++)
                A[mt][kh] = *(const v8h*)(wp + (mt * 2 + kh) * 512);
        const float* cb = cf + l * 192;
        v4f bias[4];
#pragma unroll
        for (int mt = 0; mt < 4; mt++)
            bias[mt] = *(const v4f*)(cb + mt * 16 + q * 4);
#pragma unroll
        for (int ti = 0; ti < 4; ti++) {
            v4f D[4];
#pragma unroll
            for (int mt = 0; mt < 4; mt++) {
                D[mt] = __builtin_amdgcn_mfma_f32_16x16x32_f16(A[mt][0], b0[ti], bias[mt], 0, 0, 0);
                D[mt] = __builtin_amdgcn_mfma_f32_16x16x32_f16(A[mt][1], b1[ti], D[mt], 0, 0, 0);
            }
            layer_epilogue(D, cb, q, &b0[ti], &b1[ti]);
        }
    }

    // ---- layer 4: 64 -> 3 (rows physical, padded to 16) ----
    {
        const _Float16* wp = img + 14336 + lane * 8;
        v8h A0 = *(const v8h*)(wp);
        v8h A1 = *(const v8h*)(wp + 512);
        v4f b4i = {cf[768], cf[769], cf[770], 0.0f};
#pragma unroll
        for (int ti = 0; ti < 4; ti++) {
            v4f D = __builtin_amdgcn_mfma_f32_16x16x32_f16(A0, b0[ti], b4i, 0, 0, 0);
            D = __builtin_amdgcn_mfma_f32_16x16x32_f16(A1, b1[ti], D, 0, 0, 0);
            int p = wbase + ti * 16 + c;
            if (q == 0 && p < end) {
                float* op = out + (size_t)sid[ti] * 3;
                op[0] = D[0]; op[1] = D[1]; op[2] = D[2];
            }
        }
    }
}

// -------------------------------------------------------------- launch ----
extern "C" void kernel_launch(void* const* d_in, const int* in_sizes, int n_in,
                              void* d_out, int out_size, void* d_ws, size_t ws_size,
                              hipStream_t stream) {
    const float* x  = (const float*)d_in[0];
    const int*  idx = (const int*)d_in[1];
    const float* W0 = (const float*)d_in[2];
    const float* B0 = (const float*)d_in[3];
    const float* G0 = (const float*)d_in[4];
    const float* H0 = (const float*)d_in[5];
    const float* W1 = (const float*)d_in[6];
    const float* B1 = (const float*)d_in[7];
    const float* G1 = (const float*)d_in[8];
    const float* H1 = (const float*)d_in[9];
    const float* W2 = (const float*)d_in[10];
    const float* B2 = (const float*)d_in[11];
    const float* G2 = (const float*)d_in[12];
    const float* H2 = (const float*)d_in[13];
    const float* W3 = (const float*)d_in[14];
    const float* B3 = (const float*)d_in[15];
    const float* G3 = (const float*)d_in[16];
    const float* H3 = (const float*)d_in[17];
    const float* W4 = (const float*)d_in[18];
    const float* B4 = (const float*)d_in[19];
    float* out = (float*)d_out;

    int n = in_sizes[1];
    int* iws = (int*)d_ws;
    _Float16* xs = (_Float16*)((char*)d_ws + (size_t)IWS_INTS * 4);
    unsigned char* imgbase =
        (unsigned char*)d_ws + (size_t)IWS_INTS * 4 + (size_t)NM * CAP * 16;

    (void)hipMemsetAsync(d_ws, 0, NM * CSTRIDE * sizeof(int), stream);
    bucket_img_kernel<<<dim3(NBLKB), 256, 0, stream>>>(
        idx, x, n, W0, W1, W2, W3, W4,
        B0, G0, H0, B1, G1, H1, B2, G2, H2, B3, G3, H3, B4, iws, xs, imgbase);
    // grid.x = ceil(CAP/256) = 19 chunks of 256 samples per model.
    mlp_kernel<<<dim3(19, NM), 256, 0, stream>>>(iws, xs, imgbase, out);
}